// Round 7
// baseline (10641.547 us; speedup 1.0000x reference)
//
#include <hip/hip_runtime.h>
#include <stdint.h>
#include <stddef.h>

// Problem constants (ESN_58317065945127)
#define B_    128
#define T_    2048
#define D_    128
#define H_    1024
#define O_    32
#define LAST_ 20

// Partition: 8 batch-blocks x 8 col-blocks = 64 WGs of 256 threads.
// Each wave owns [16 batch x 32 col] (two 16-col MFMA tiles sharing B-frags).
// Theory: step time ~ coherent-read burst volume (fabric ~2-2.5 TB/s for the
// per-step thundering herd). 32 cols/wave halves staged volume 4->2 MB.
#define NB_   8
#define NC_   8
#define RING_ 4

typedef __bf16 bf16x8 __attribute__((ext_vector_type(8)));
typedef __bf16 bf16x4 __attribute__((ext_vector_type(4)));
typedef float  f32x4  __attribute__((ext_vector_type(4)));

union Pack8  { unsigned long long u;    bf16x4 v; };
union Pack16 { unsigned long long u[2]; bf16x8 v; };

__device__ __forceinline__ float tanh_fast(float s) {
    float a = fminf(fmaxf(s, -12.0f), 12.0f);
    float e = __expf(2.0f * a);
    return (e - 1.0f) / (e + 1.0f);
}

// Cross-WG traffic via relaxed AGENT-scope atomics (individual sc0/sc1 ops,
// no cache-wide wbl2/inv — R1 lesson). Release = publish -> vmcnt(0) -> flag.
// The publish vmcnt(0) covers ONLY the 2 publish stores — x prefetch loads
// are issued AFTER the flag store (consumed behind the next poll).
__global__ __launch_bounds__(256, 1) void esn_persist(
    const float* __restrict__ x, const float* __restrict__ w_in,
    const float* __restrict__ w_r, __bf16* __restrict__ h_ex,
    float* __restrict__ hs, int* __restrict__ flags)
{
    __shared__ bf16x8 ls[2][16][128];   // 2 bufs x 16 batch-rows x 128 16B chunks = 64 KiB

    const int wg  = (int)blockIdx.x;
    const int bb  = wg & (NB_ - 1);  // cohort id; &7 co-lands cohort on one XCD (perf only)
    const int cb  = wg >> 3;
    const int tid = (int)threadIdx.x;
    const int wv  = tid >> 6;
    const int ln  = tid & 63;
    const int nn  = ln & 15;   // batch index within tile
    const int q   = ln >> 4;   // quad
    const int b0  = bb * 16;
    const int n0  = cb * 128 + wv * 32;   // 32 cols per wave (two 16-col tiles)

    // ---- one-time: weight fragments into registers (A-operand layout) ----
    bf16x8 win[2][4];                    // w_in cols, 2 tiles x 4 K-chunks
    #pragma unroll
    for (int tt = 0; tt < 2; ++tt)
        #pragma unroll
        for (int c = 0; c < 4; ++c) {
            bf16x8 f;
            #pragma unroll
            for (int j = 0; j < 8; ++j)
                f[j] = (__bf16)w_in[(size_t)(c * 32 + q * 8 + j) * H_
                                    + (n0 + tt * 16 + nn)];
            win[tt][c] = f;
        }
    bf16x8 wr[2][32];                    // w_r cols, 2 tiles x 32 K-chunks (256 regs)
    #pragma unroll
    for (int tt = 0; tt < 2; ++tt)
        #pragma unroll
        for (int kc = 0; kc < 32; ++kc) {
            bf16x8 f;
            #pragma unroll
            for (int j = 0; j < 8; ++j)
                f[j] = (__bf16)w_r[(size_t)(kc * 32 + q * 8 + j) * H_
                                   + (n0 + tt * 16 + nn)];
            wr[tt][kc] = f;
        }

    // Spin deadline ~3s, checked every 256 sleeps (off the fast path).
    const unsigned long long tdead =
        __builtin_amdgcn_s_memrealtime() + 300000000ull;

    int* cfl    = flags + bb * 32;            // the 32 wave-flags of my cohort
    int* myflag = cfl + (cb * 4 + wv);
    const float* xrow = x + (size_t)(b0 + nn) * T_ * D_ + q * 8;  // x[b][t][k]
    const size_t hrow = (size_t)(b0 + nn) * H_;

    // x prefetch: xn holds fp32 x(t); loads for t+1 are issued post-flag.
    f32x4 xn[8];
    #pragma unroll
    for (int c = 0; c < 4; ++c) {
        xn[2 * c]     = *(const f32x4*)(xrow + c * 32);
        xn[2 * c + 1] = *(const f32x4*)(xrow + c * 32 + 4);
    }

    float hm[2][4];                      // fp32 master h, 2 tiles x 4 cols
    #pragma unroll
    for (int tt = 0; tt < 2; ++tt)
        #pragma unroll
        for (int r = 0; r < 4; ++r) hm[tt][r] = 0.f;

    for (int t = 0; t < T_; ++t) {
        f32x4 c00 = {0,0,0,0}, c01 = {0,0,0,0};   // tile0 chains
        f32x4 c10 = {0,0,0,0}, c11 = {0,0,0,0};   // tile1 chains

        if (t > 0) {
            // ---- poll cohort flags: fast first check, then sleep loop ----
            const int want = t - 1;
            int f = __hip_atomic_load(cfl + (ln & 31), __ATOMIC_RELAXED,
                                      __HIP_MEMORY_SCOPE_AGENT);
            if (!__all(f >= want)) {
                int spins = 0;
                for (;;) {
                    __builtin_amdgcn_s_sleep(1);
                    f = __hip_atomic_load(cfl + (ln & 31), __ATOMIC_RELAXED,
                                          __HIP_MEMORY_SCOPE_AGENT);
                    if (__all(f >= want)) break;
                    if (((++spins) & 255) == 0 &&
                        __builtin_amdgcn_s_memrealtime() > tdead) break;  // anti-hang
                }
            }

            // ---- stage h(t-1) into LDS: wave wv loads its 8KB quarter ----
            const int sb = (t - 1) & 1;
            const __bf16* hbase = h_ex
                + (size_t)((t - 1) & (RING_ - 1)) * (B_ * H_) + (size_t)b0 * H_;
            Pack16 pk[8];
            #pragma unroll
            for (int i = 0; i < 8; ++i) {
                const int p = wv * 512 + i * 64 + ln;   // 16B piece index
                const unsigned long long* gp = (const unsigned long long*)
                    (hbase + (size_t)(p >> 7) * H_ + (p & 127) * 8);
                pk[i].u[0] = __hip_atomic_load(gp, __ATOMIC_RELAXED,
                                               __HIP_MEMORY_SCOPE_AGENT);
                pk[i].u[1] = __hip_atomic_load(gp + 1, __ATOMIC_RELAXED,
                                               __HIP_MEMORY_SCOPE_AGENT);
            }
            asm volatile("" ::: "memory");  // keep all issues ahead of the writes
            #pragma unroll
            for (int i = 0; i < 8; ++i) {
                const int p = wv * 512 + i * 64 + ln;
                const int r = p >> 7, ch = p & 127;
                ls[sb][r][ch ^ (r & 7)] = pk[i].v;   // XOR swizzle
            }

            // x bf16 conversion + projection MFMAs before the barrier
            bf16x8 xf[4];
            #pragma unroll
            for (int c = 0; c < 4; ++c) {
                bf16x8 fb;
                #pragma unroll
                for (int j = 0; j < 4; ++j) {
                    fb[j]     = (__bf16)xn[2 * c][j];
                    fb[j + 4] = (__bf16)xn[2 * c + 1][j];
                }
                xf[c] = fb;
            }
            #pragma unroll
            for (int c = 0; c < 4; ++c) {
                c00 = __builtin_amdgcn_mfma_f32_16x16x32_bf16(win[0][c], xf[c], c00, 0, 0, 0);
                c10 = __builtin_amdgcn_mfma_f32_16x16x32_bf16(win[1][c], xf[c], c10, 0, 0, 0);
            }

            __syncthreads();

            // ---- recurrent MFMAs: shared B-frag feeds both col-tiles ----
            #pragma unroll
            for (int kc = 0; kc < 32; ++kc) {
                bf16x8 a = ls[sb][nn][(kc * 4 + q) ^ (nn & 7)];
                if (kc & 1) {
                    c01 = __builtin_amdgcn_mfma_f32_16x16x32_bf16(wr[0][kc], a, c01, 0, 0, 0);
                    c11 = __builtin_amdgcn_mfma_f32_16x16x32_bf16(wr[1][kc], a, c11, 0, 0, 0);
                } else {
                    c00 = __builtin_amdgcn_mfma_f32_16x16x32_bf16(wr[0][kc], a, c00, 0, 0, 0);
                    c10 = __builtin_amdgcn_mfma_f32_16x16x32_bf16(wr[1][kc], a, c10, 0, 0, 0);
                }
            }
        } else {
            bf16x8 xf[4];
            #pragma unroll
            for (int c = 0; c < 4; ++c) {
                bf16x8 fb;
                #pragma unroll
                for (int j = 0; j < 4; ++j) {
                    fb[j]     = (__bf16)xn[2 * c][j];
                    fb[j + 4] = (__bf16)xn[2 * c + 1][j];
                }
                xf[c] = fb;
            }
            #pragma unroll
            for (int c = 0; c < 4; ++c) {
                c00 = __builtin_amdgcn_mfma_f32_16x16x32_bf16(win[0][c], xf[c], c00, 0, 0, 0);
                c10 = __builtin_amdgcn_mfma_f32_16x16x32_bf16(win[1][c], xf[c], c10, 0, 0, 0);
            }
        }

        const f32x4 a0 = c00 + c01;
        const f32x4 a1 = c10 + c11;
        #pragma unroll
        for (int r = 0; r < 4; ++r) {
            const float t0 = tanh_fast(a0[r]);
            const float t1 = tanh_fast(a1[r]);
            if (t == 0) { hm[0][r] = t0;                      hm[1][r] = t1; }
            else        { hm[0][r] = 0.1f * hm[0][r] + 0.9f * t0;
                          hm[1][r] = 0.1f * hm[1][r] + 0.9f * t1; }
        }

        // publish: two packed 8B sc1 stores (tile0, tile1)
        {
            __bf16* slot = h_ex + (size_t)(t & (RING_ - 1)) * (B_ * H_) + hrow;
            #pragma unroll
            for (int tt = 0; tt < 2; ++tt) {
                Pack8 p;
                p.v = (bf16x4){(__bf16)hm[tt][0], (__bf16)hm[tt][1],
                               (__bf16)hm[tt][2], (__bf16)hm[tt][3]};
                __hip_atomic_store((unsigned long long*)
                                       (slot + n0 + tt * 16 + q * 4),
                                   p.u, __ATOMIC_RELAXED,
                                   __HIP_MEMORY_SCOPE_AGENT);
            }
        }
        // ack covers ONLY the publish stores (x loads not yet issued)
        asm volatile("s_waitcnt vmcnt(0)" ::: "memory");
        if (ln == 0)
            __hip_atomic_store(myflag, t, __ATOMIC_RELAXED,
                               __HIP_MEMORY_SCOPE_AGENT);

        // ---- off the critical path ----
        if (t >= T_ - LAST_) {           // tail collection (fp32)
            // R6 BUG WAS HERE: missing +q*4 made all quads alias q=0's slot,
            // leaving 0xAA poison in 3/4 of hs. Lane's cols for tile tt are
            // n0 + tt*16 + q*4 + r  — must match the publish addressing.
            float* sp = hs + (size_t)(t - (T_ - LAST_)) * (B_ * H_) + hrow;
            *(f32x4*)(sp + n0 + q * 4)
                = (f32x4){hm[0][0], hm[0][1], hm[0][2], hm[0][3]};
            *(f32x4*)(sp + n0 + 16 + q * 4)
                = (f32x4){hm[1][0], hm[1][1], hm[1][2], hm[1][3]};
        }
        if (t + 1 < T_) {                // issue x loads for t+1 (fly thru next poll)
            const float* xp = xrow + (size_t)(t + 1) * D_;
            #pragma unroll
            for (int c = 0; c < 4; ++c) {
                xn[2 * c]     = *(const f32x4*)(xp + c * 32);
                xn[2 * c + 1] = *(const f32x4*)(xp + c * 32 + 4);
            }
        }
    }
}

// Readout: out[b,:] = cat(hs)[b,:] @ W + bias.  One block per batch row.
__global__ __launch_bounds__(256) void esn_out(
    const float* __restrict__ hs, const float* __restrict__ Wm,
    const float* __restrict__ bias, float* __restrict__ out)
{
    const int b   = (int)blockIdx.x;
    const int tid = (int)threadIdx.x;
    float acc[O_];
    #pragma unroll
    for (int o = 0; o < O_; ++o) acc[o] = 0.f;

    for (int k = tid; k < LAST_ * H_; k += 256) {
        // cat order: k = t'*H + c  <->  hs[t'][b][c]
        const float hv = hs[(size_t)(k >> 10) * (B_ * H_) + (size_t)b * H_ + (k & (H_ - 1))];
        const f32x4* wp = (const f32x4*)(Wm + (size_t)k * O_);
        #pragma unroll
        for (int v = 0; v < 8; ++v) {
            f32x4 w4 = wp[v];
            acc[4 * v + 0] = fmaf(hv, w4[0], acc[4 * v + 0]);
            acc[4 * v + 1] = fmaf(hv, w4[1], acc[4 * v + 1]);
            acc[4 * v + 2] = fmaf(hv, w4[2], acc[4 * v + 2]);
            acc[4 * v + 3] = fmaf(hv, w4[3], acc[4 * v + 3]);
        }
    }

    __shared__ float red[256][O_ + 1];  // +1 pad: conflict-free column sums
    #pragma unroll
    for (int o = 0; o < O_; ++o) red[tid][o] = acc[o];
    __syncthreads();
    if (tid < O_) {
        float s = bias[tid];
        for (int i = 0; i < 256; ++i) s += red[i][tid];
        out[(size_t)b * O_ + tid] = s;
    }
}

extern "C" void kernel_launch(void* const* d_in, const int* in_sizes, int n_in,
                              void* d_out, int out_size, void* d_ws, size_t ws_size,
                              hipStream_t stream)
{
    const float* x    = (const float*)d_in[0];  // [128,2048,128]
    const float* w_in = (const float*)d_in[1];  // [128,1024]
    const float* w_r  = (const float*)d_in[2];  // [1024,1024]
    const float* Wm   = (const float*)d_in[3];  // [20480,32]
    const float* bias = (const float*)d_in[4];  // [32]
    float* out        = (float*)d_out;          // [128,32]

    const size_t flag_bytes = 4096;                                      // 256 ints used
    const size_t hex_bytes  = (size_t)RING_ * B_ * H_ * sizeof(__bf16);  // 1 MiB
    const size_t hs_bytes   = (size_t)LAST_ * B_ * H_ * sizeof(float);   // 10 MiB
    if (ws_size < flag_bytes + hex_bytes + hs_bytes) return;  // fail loud, not corrupt

    int*    flags = (int*)d_ws;
    __bf16* h_ex  = (__bf16*)((char*)d_ws + flag_bytes);
    float*  hs    = (float*)((char*)d_ws + flag_bytes + hex_bytes);

    // flags = -1 ("nothing published"); ws is re-poisoned 0xAA before every call
    hipMemsetAsync(flags, 0xFF, flag_bytes, stream);

    hipLaunchKernelGGL(esn_persist, dim3(NB_ * NC_), dim3(256), 0, stream,
                       x, w_in, w_r, h_ex, hs, flags);
    hipLaunchKernelGGL(esn_out, dim3(B_), dim3(256), 0, stream,
                       hs, Wm, bias, out);
}